// Round 7
// baseline (817.775 us; speedup 1.0000x reference)
//
#include <hip/hip_runtime.h>
#include <hip/hip_bf16.h>
#include <stdint.h>

#define NTOK 8192
#define NE 8
#define DIN 1024
#define DH 4096
#define DOUT 1024
#define MAXMB 135  // max total m-blocks: 16384/128 + 7 partial tails

typedef __bf16 bf16;
typedef __bf16 bf16_8 __attribute__((ext_vector_type(8)));
typedef __bf16 bf16_4 __attribute__((ext_vector_type(4)));
typedef float f32_4 __attribute__((ext_vector_type(4)));

__device__ __forceinline__ void gl_lds16(const void* g, void* l) {
  __builtin_amdgcn_global_load_lds(
      (const __attribute__((address_space(1))) unsigned int*)g,
      (__attribute__((address_space(3))) unsigned int*)l, 16, 0, 0);
}

// ---- gating: fp32 logits, top-2, softmax; fused x->bf16 AND bias prefill ---
// After the butterfly reduce every lane holds the full logit sums, so top-2 is
// computed redundantly in all lanes; lane0 writes topi/topw, all lanes write
// out[t] = w0*b2[e0] + w1*b2[e1] (replaces the separate prefill kernel).
__global__ void gate_kernel(const float* __restrict__ x, const float* __restrict__ Wg,
                            const float* __restrict__ bg, const float* __restrict__ b2,
                            int* __restrict__ topi, float* __restrict__ topw,
                            bf16* __restrict__ xb, float* __restrict__ out) {
  int t = blockIdx.x * 4 + (threadIdx.x >> 6);
  int lane = threadIdx.x & 63;
  float acc[NE];
#pragma unroll
  for (int e = 0; e < NE; e++) acc[e] = 0.f;
  const float* xr = x + (size_t)t * DIN;
  bf16* xw = xb + (size_t)t * DIN;
#pragma unroll
  for (int i = 0; i < DIN / 64; i++) {
    float xv = xr[lane + 64 * i];
    xw[lane + 64 * i] = (bf16)xv;  // fused fp32->bf16 conversion
    const float4* wr = (const float4*)(Wg + (size_t)(lane + 64 * i) * NE);
    float4 w0 = wr[0], w1 = wr[1];
    acc[0] += xv * w0.x; acc[1] += xv * w0.y; acc[2] += xv * w0.z; acc[3] += xv * w0.w;
    acc[4] += xv * w1.x; acc[5] += xv * w1.y; acc[6] += xv * w1.z; acc[7] += xv * w1.w;
  }
#pragma unroll
  for (int off = 32; off > 0; off >>= 1)
#pragma unroll
    for (int e = 0; e < NE; e++) acc[e] += __shfl_xor(acc[e], off, 64);
  // all lanes now hold identical sums -> redundant top-2 in every lane
  float lg[NE];
#pragma unroll
  for (int e = 0; e < NE; e++) lg[e] = acc[e] + bg[e];
  int i0 = 0; float v0 = lg[0];
#pragma unroll
  for (int e = 1; e < NE; e++) if (lg[e] > v0) { v0 = lg[e]; i0 = e; }
  int i1 = -1; float v1 = -3.0e38f;
#pragma unroll
  for (int e = 0; e < NE; e++) if (e != i0 && lg[e] > v1) { v1 = lg[e]; i1 = e; }
  float ex = expf(v1 - v0);
  float w0 = 1.f / (1.f + ex);
  float w1 = ex / (1.f + ex);
  if (lane == 0) {
    topi[2 * t] = i0; topi[2 * t + 1] = i1;
    topw[2 * t] = w0; topw[2 * t + 1] = w1;
  }
  // fused prefill: out[t] = w0*b2[i0] + w1*b2[i1]  (b2 is 32KB, L2-hot)
  const float* p0 = b2 + (size_t)i0 * DOUT;
  const float* p1 = b2 + (size_t)i1 * DOUT;
  float* orow = out + (size_t)t * DOUT;
#pragma unroll
  for (int c = 0; c < DOUT / 256; c++) {
    int idx = (lane + c * 64) * 4;
    float4 a = *(const float4*)(p0 + idx);
    float4 b = *(const float4*)(p1 + idx);
    float4 o;
    o.x = w0 * a.x + w1 * b.x; o.y = w0 * a.y + w1 * b.y;
    o.z = w0 * a.z + w1 * b.z; o.w = w0 * a.w + w1 * b.w;
    *(float4*)(orow + idx) = o;
  }
}

// ---- prep: single-block counting sort (replaces memset+hist+scan+pack) ----
// 256 threads x 64 tokens. All counters live in LDS (avoid dynamic-index
// register arrays -> scratch). Exclusive prefix per expert via 8-lane serial
// scan; pack phase bumps LDS cursors (2-way bank max = free).
__global__ __launch_bounds__(256) void prep_kernel(
    const int* __restrict__ topi, const float* __restrict__ topw,
    int* __restrict__ counts, int* __restrict__ offsets, int* __restrict__ mblk_off,
    int* __restrict__ tok_list, float* __restrict__ wt_list) {
  __shared__ int cnt[NE][256];
  __shared__ int off_l[NE], tot[NE];
  int t = threadIdx.x;
#pragma unroll
  for (int e = 0; e < NE; e++) cnt[e][t] = 0;
  __syncthreads();
  int base = t * 64;
  for (int j = 0; j < 64; j++) cnt[topi[base + j]][t]++;
  __syncthreads();
  if (t < NE) {
    int s = 0;
    for (int i = 0; i < 256; i++) { int v = cnt[t][i]; cnt[t][i] = s; s += v; }
    tot[t] = s; counts[t] = s;
  }
  __syncthreads();
  if (t == 0) {
    int s = 0, b = 0;
    for (int e = 0; e < NE; e++) {
      off_l[e] = s; offsets[e] = s; mblk_off[e] = b;
      s += tot[e]; b += (tot[e] + 127) >> 7;
    }
    mblk_off[NE] = b;
  }
  __syncthreads();
  for (int j = 0; j < 64; j++) {
    int i = base + j;
    int e = topi[i];
    int slot = off_l[e] + cnt[e][t]++;
    tok_list[slot] = i >> 1;
    wt_list[slot] = topw[i];
  }
}

// ---------------- fused weight transpose + fp32->bf16, 64x64 tiles ----------
__global__ __launch_bounds__(256) void wt_kernel(
    const float* __restrict__ W1, const float* __restrict__ W2,
    bf16* __restrict__ W1t, bf16* __restrict__ W2t, int hchunk, int hc0) {
  __shared__ bf16 tile[64][66];
  int idx = blockIdx.x;
  int e = blockIdx.z;
  const float* src; bf16* dst; int sld, dld;
  if (blockIdx.y == 0) {
    int nkt = DIN / 64;  // 16
    int tk = idx % nkt, tn = idx / nkt;
    src = W1 + (size_t)e * DIN * DH + (size_t)(tk * 64) * DH + hc0 + tn * 64;
    dst = W1t + (size_t)e * hchunk * DIN + (size_t)(tn * 64) * DIN + tk * 64;
    sld = DH; dld = DIN;
  } else {
    int nkt = hchunk / 64;
    int tk = idx % nkt, tn = idx / nkt;
    src = W2 + (size_t)e * DH * DOUT + (size_t)(hc0 + tk * 64) * DOUT + tn * 64;
    dst = W2t + (size_t)e * DOUT * hchunk + (size_t)(tn * 64) * hchunk + tk * 64;
    sld = DOUT; dld = hchunk;
  }
  int tid = threadIdx.x;
  int r = tid >> 4, c = (tid & 15) * 4;
#pragma unroll
  for (int p = 0; p < 4; p++) {
    float4 v = *(const float4*)(src + (size_t)(p * 16 + r) * sld + c);
    bf16_4 b;
    b[0] = (bf16)v.x; b[1] = (bf16)v.y; b[2] = (bf16)v.z; b[3] = (bf16)v.w;
    *(bf16_4*)(&tile[p * 16 + r][c]) = b;
  }
  __syncthreads();
  int n = tid >> 3, k8 = (tid & 7) * 8;
#pragma unroll
  for (int p = 0; p < 2; p++) {
    int nn = p * 32 + n;
    bf16_8 o;
#pragma unroll
    for (int j = 0; j < 8; j++) o[j] = tile[k8 + j][nn];
    *(bf16_8*)(dst + (size_t)nn * dld + k8) = o;
  }
}

// Pipeline (quad-buffer): 4 LDS bufs; prologue stages tiles 0-2; iter kt:
// counted vmcnt wait (8 steady / 4 at nk-2 / 0 last), barrier, stage tile kt+3
// into buf (kt+3)&3, compute buf kt&3. Issue->wait distance = 3 iterations.
// Hazard: buf (kt+3)&3 = (kt-1)&3 was last read in iter kt-1; those ds_reads
// were consumed (MFMA-issued) before their wave crossed barrier(kt). Safe.

// ---------------- GEMM1: h = relu(gather(xb) @ W1t^T + b1) ------------------
__global__ __launch_bounds__(256) void gemm1_kernel(
    const bf16* __restrict__ xb, const bf16* __restrict__ W1t,
    const float* __restrict__ b1, const int* __restrict__ counts,
    const int* __restrict__ offsets, const int* __restrict__ mblk_off,
    const int* __restrict__ tok_list,
    bf16* __restrict__ h, int hchunk, int hc0) {
  int nbx = gridDim.x;
  int orig = blockIdx.y * nbx + blockIdx.x;
  int nwg = nbx * gridDim.y;
  int wgid = (orig & 7) * (nwg >> 3) + (orig >> 3);
  int bxi = wgid % nbx;
  int mb = wgid / nbx;
  if (mb >= mblk_off[NE]) return;
  int e = 0;
  while (mb >= mblk_off[e + 1]) e++;
  int ne = counts[e];
  int m0 = (mb - mblk_off[e]) * 128;
  int off = offsets[e];
  int n0 = bxi * 128;

  __shared__ __align__(16) bf16 smem[8 * 4096];  // 64 KB: 4 bufs x (A+B)
  bf16* ldsA = smem;
  bf16* ldsB = smem + 4 * 4096;

  int tid = threadIdx.x;
  int w = tid >> 6, lane = tid & 63;
  int scol = (((lane & 3) ^ (lane >> 3)) & 3) * 8;  // swizzled 16B col for staging

  const bf16* gA[2]; const bf16* gB[2];
  bf16* lA[2]; bf16* lB[2];
#pragma unroll
  for (int j = 0; j < 2; j++) {
    int seg = w * 2 + j;
    int row = seg * 16 + (lane >> 2);
    int slot = off + m0 + row;
    int smax = off + ne - 1;
    if (slot > smax) slot = smax;           // clamp tail rows to a valid token
    int tok = tok_list[slot];
    gA[j] = xb + (size_t)tok * DIN + scol;
    lA[j] = ldsA + seg * 512;               // wave-uniform base; HW adds lane*16B
    gB[j] = W1t + ((size_t)e * hchunk + n0 + row) * DIN + scol;
    lB[j] = ldsB + seg * 512;
  }

  f32_4 acc[4][4];
#pragma unroll
  for (int i = 0; i < 4; i++)
#pragma unroll
    for (int j = 0; j < 4; j++) acc[i][j] = (f32_4){0.f, 0.f, 0.f, 0.f};

  int wm = w & 1, wn = w >> 1;
  int lr = lane & 15, quad = lane >> 4;
  int rcol = ((quad ^ (lr >> 1)) & 3) * 8;

  auto compute = [&](int buf) {
    bf16_8 af[4], bfr[4];
#pragma unroll
    for (int mt = 0; mt < 4; mt++)
      af[mt] = *(const bf16_8*)(ldsA + buf * 4096 + (wm * 64 + mt * 16 + lr) * 32 + rcol);
#pragma unroll
    for (int nt = 0; nt < 4; nt++)
      bfr[nt] = *(const bf16_8*)(ldsB + buf * 4096 + (wn * 64 + nt * 16 + lr) * 32 + rcol);
#pragma unroll
    for (int mt = 0; mt < 4; mt++)
#pragma unroll
      for (int nt = 0; nt < 4; nt++)
        acc[mt][nt] = __builtin_amdgcn_mfma_f32_16x16x32_bf16(af[mt], bfr[nt], acc[mt][nt], 0, 0, 0);
  };

  const int nk = DIN / 32;
  // prologue: stage tiles 0,1,2 into bufs 0,1,2
#pragma unroll
  for (int tp = 0; tp < 3; tp++) {
#pragma unroll
    for (int j = 0; j < 2; j++) { gl_lds16(gA[j], lA[j] + tp * 4096); gl_lds16(gB[j], lB[j] + tp * 4096); }
    gA[0] += 32; gA[1] += 32; gB[0] += 32; gB[1] += 32;
  }

  for (int kt = 0; kt < nk; kt++) {
    if (kt < nk - 2)       asm volatile("s_waitcnt vmcnt(8)" ::: "memory");
    else if (kt == nk - 2) asm volatile("s_waitcnt vmcnt(4)" ::: "memory");
    else                   asm volatile("s_waitcnt vmcnt(0)" ::: "memory");
    __builtin_amdgcn_s_barrier();
    __builtin_amdgcn_sched_barrier(0);
    if (kt < nk - 3) {
      int sb = (kt + 3) & 3;
#pragma unroll
      for (int j = 0; j < 2; j++) {
        gl_lds16(gA[j], lA[j] + sb * 4096);
        gl_lds16(gB[j], lB[j] + sb * 4096);
      }
      gA[0] += 32; gA[1] += 32; gB[0] += 32; gB[1] += 32;
    }
    __builtin_amdgcn_sched_barrier(0);
    compute(kt & 3);
  }

  // ---- epilogue: bounce C tile through LDS for coalesced 16B stores --------
  __syncthreads();  // all waves done with K-loop LDS; smem is free
#pragma unroll
  for (int nt = 0; nt < 4; nt++) {
    int cloc = wn * 64 + nt * 16 + lr;
    float bias = b1[(size_t)e * DH + hc0 + n0 + cloc];
#pragma unroll
    for (int mt = 0; mt < 4; mt++) {
#pragma unroll
      for (int r2 = 0; r2 < 4; r2++) {
        int row = wm * 64 + mt * 16 + quad * 4 + r2;
        float v = acc[mt][nt][r2] + bias;
        v = v > 0.f ? v : 0.f;
        int byte = (row * 256 + cloc * 2) ^ (((row >> 2) & 7) << 4);
        *(bf16*)((char*)smem + byte) = (bf16)v;
      }
    }
  }
  __syncthreads();
#pragma unroll
  for (int p = 0; p < 8; p++) {
    int r = p * 16 + (tid >> 4);
    int b = tid & 15;
    if (m0 + r < ne) {
      int byte = (r * 256 + b * 16) ^ (((r >> 2) & 7) << 4);
      bf16_8 v = *(const bf16_8*)((char*)smem + byte);
      *(bf16_8*)(h + (size_t)(off + m0 + r) * hchunk + n0 + b * 8) = v;
    }
  }
}

// ---------------- GEMM2: out[tok] += w_slot * (h @ W2t^T)  (fp32 atomics) ---
__global__ __launch_bounds__(256) void gemm2_kernel(
    const bf16* __restrict__ h, const bf16* __restrict__ W2t,
    const int* __restrict__ counts, const int* __restrict__ offsets,
    const int* __restrict__ mblk_off, const int* __restrict__ tok_list,
    const float* __restrict__ wt_list,
    float* __restrict__ out, int hchunk) {
  int nbx = gridDim.x;
  int orig = blockIdx.y * nbx + blockIdx.x;
  int nwg = nbx * gridDim.y;
  int wgid = (orig & 7) * (nwg >> 3) + (orig >> 3);
  int bxi = wgid % nbx;
  int mb = wgid / nbx;
  if (mb >= mblk_off[NE]) return;
  int e = 0;
  while (mb >= mblk_off[e + 1]) e++;
  int ne = counts[e];
  int m0 = (mb - mblk_off[e]) * 128;
  int off = offsets[e];
  int n0 = bxi * 128;

  __shared__ __align__(16) bf16 smem[8 * 4096];  // 64 KB
  bf16* ldsA = smem;
  bf16* ldsB = smem + 4 * 4096;

  int tid = threadIdx.x;
  int w = tid >> 6, lane = tid & 63;
  int scol = (((lane & 3) ^ (lane >> 3)) & 3) * 8;

  const bf16* gA[2]; const bf16* gB[2];
  bf16* lA[2]; bf16* lB[2];
#pragma unroll
  for (int j = 0; j < 2; j++) {
    int seg = w * 2 + j;
    int row = seg * 16 + (lane >> 2);
    gA[j] = h + (size_t)(off + m0 + row) * hchunk + scol;  // h padded +128 rows
    lA[j] = ldsA + seg * 512;
    gB[j] = W2t + ((size_t)e * DOUT + n0 + row) * hchunk + scol;
    lB[j] = ldsB + seg * 512;
  }

  f32_4 acc[4][4];
#pragma unroll
  for (int i = 0; i < 4; i++)
#pragma unroll
    for (int j = 0; j < 4; j++) acc[i][j] = (f32_4){0.f, 0.f, 0.f, 0.f};

  int wm = w & 1, wn = w >> 1;
  int lr = lane & 15, quad = lane >> 4;
  int rcol = ((quad ^ (lr >> 1)) & 3) * 8;

  auto compute = [&](int buf) {
    bf16_8 af[4], bfr[4];
#pragma unroll
    for (int mt = 0; mt < 4; mt++)
      af[mt] = *(const bf16_8*)(ldsA + buf * 4096 + (wm * 64 + mt * 16 + lr) * 32 + rcol);
#pragma unroll
    for (int nt = 0; nt < 4; nt++)
      bfr[nt] = *(const bf16_8*)(ldsB + buf * 4096 + (wn * 64 + nt * 16 + lr) * 32 + rcol);
#pragma unroll
    for (int mt = 0; mt < 4; mt++)
#pragma unroll
      for (int nt = 0; nt < 4; nt++)
        acc[mt][nt] = __builtin_amdgcn_mfma_f32_16x16x32_bf16(af[mt], bfr[nt], acc[mt][nt], 0, 0, 0);
  };

  const int nk = hchunk / 32;
  // prologue: stage tiles 0,1,2 into bufs 0,1,2
#pragma unroll
  for (int tp = 0; tp < 3; tp++) {
#pragma unroll
    for (int j = 0; j < 2; j++) { gl_lds16(gA[j], lA[j] + tp * 4096); gl_lds16(gB[j], lB[j] + tp * 4096); }
    gA[0] += 32; gA[1] += 32; gB[0] += 32; gB[1] += 32;
  }

  for (int kt = 0; kt < nk; kt++) {
    if (kt < nk - 2)       asm volatile("s_waitcnt vmcnt(8)" ::: "memory");
    else if (kt == nk - 2) asm volatile("s_waitcnt vmcnt(4)" ::: "memory");
    else                   asm volatile("s_waitcnt vmcnt(0)" ::: "memory");
    __builtin_amdgcn_s_barrier();
    __builtin_amdgcn_sched_barrier(0);
    if (kt < nk - 3) {
      int sb = (kt + 3) & 3;
#pragma unroll
      for (int j = 0; j < 2; j++) {
        gl_lds16(gA[j], lA[j] + sb * 4096);
        gl_lds16(gB[j], lB[j] + sb * 4096);
      }
      gA[0] += 32; gA[1] += 32; gB[0] += 32; gB[1] += 32;
    }
    __builtin_amdgcn_sched_barrier(0);
    compute(kt & 3);
  }

  // ---- epilogue: weighted atomic accumulate directly into out --------------
#pragma unroll
  for (int mt = 0; mt < 4; mt++) {
#pragma unroll
    for (int r2 = 0; r2 < 4; r2++) {
      int row = wm * 64 + mt * 16 + quad * 4 + r2;
      if (m0 + row < ne) {
        int slot = off + m0 + row;
        int tok = tok_list[slot];
        float wgt = wt_list[slot];
        float* orow = out + (size_t)tok * DOUT + n0;
#pragma unroll
        for (int nt = 0; nt < 4; nt++) {
          int c = wn * 64 + nt * 16 + lr;
          atomicAdd(orow + c, wgt * acc[mt][nt][r2]);
        }
      }
    }
  }
}

// ---------------- host ------------------------------------------------------
extern "C" void kernel_launch(void* const* d_in, const int* in_sizes, int n_in,
                              void* d_out, int out_size, void* d_ws, size_t ws_size,
                              hipStream_t stream) {
  const float* x  = (const float*)d_in[0];
  const float* Wg = (const float*)d_in[1];
  const float* bg = (const float*)d_in[2];
  const float* W1 = (const float*)d_in[3];
  const float* b1 = (const float*)d_in[4];
  const float* W2 = (const float*)d_in[5];
  const float* b2 = (const float*)d_in[6];
  float* out = (float*)d_out;

  char* p = (char*)d_ws;
  int*   counts   = (int*)p;   p += 256;
  int*   offsets  = (int*)p;   p += 256;
  int*   mblk_off = (int*)p;   p += 256;
  int*   topi     = (int*)p;   p += 16384 * 4;
  float* topw     = (float*)p; p += 16384 * 4;
  int*   tok_list = (int*)p;   p += 16384 * 4;
  float* wt_list  = (float*)p; p += 16384 * 4;
  bf16*  xb       = (bf16*)p;  p += (size_t)NTOK * DIN * 2;

  size_t fixedBytes = (size_t)(p - (char*)d_ws);
  // per-hchunk bytes: h (16384+128 rows)*2 + W1t 8*1024*2 + W2t 8*1024*2 = 65792
  int hchunk = 4096;
  while (hchunk > 128 && fixedBytes + (size_t)hchunk * 65792 > ws_size) hchunk >>= 1;

  bf16* W1t  = (bf16*)p; p += (size_t)NE * hchunk * DIN * 2;
  bf16* W2t  = (bf16*)p; p += (size_t)NE * DOUT * hchunk * 2;
  bf16* hbuf = (bf16*)p; p += (size_t)(16384 + 128) * hchunk * 2;

  gate_kernel<<<NTOK / 4, 256, 0, stream>>>(x, Wg, bg, b2, topi, topw, xb, out);
  prep_kernel<<<1, 256, 0, stream>>>(topi, topw, counts, offsets, mblk_off,
                                     tok_list, wt_list);

  int nchunks = DH / hchunk;
  for (int c = 0; c < nchunks; c++) {
    int hc0 = c * hchunk;
    int ntiles = (DIN / 64) * (hchunk / 64);
    wt_kernel<<<dim3(ntiles, 2, NE), 256, 0, stream>>>(W1, W2, W1t, W2t, hchunk, hc0);
    gemm1_kernel<<<dim3(hchunk / 128, MAXMB), 256, 0, stream>>>(
        xb, W1t, b1, counts, offsets, mblk_off, tok_list, hbuf, hchunk, hc0);
    gemm2_kernel<<<dim3(DOUT / 128, MAXMB), 256, 0, stream>>>(
        hbuf, W2t, counts, offsets, mblk_off, tok_list, wt_list, out, hchunk);
  }
}